// Round 9
// baseline (1639.610 us; speedup 1.0000x reference)
//
#include <hip/hip_runtime.h>

#define T_LEN 2048
#define DH 256

typedef short short8 __attribute__((ext_vector_type(8)));
typedef float f32x4 __attribute__((ext_vector_type(4)));

__device__ __forceinline__ unsigned short f2bf(float f) {
  unsigned u = __builtin_bit_cast(unsigned, f);
  u += 0x7fffu + ((u >> 16) & 1u);   // round-to-nearest-even
  return (unsigned short)(u >> 16);
}

// Minimal step barrier: wait this wave's LDS ops (h writes), rendezvous,
// fence the scheduler. vmcnt deliberately NOT drained: xb prefetch loads and
// h stores stay in flight across steps (no cross-wave hazard through global).
#define STEP_BARRIER() do {                                 \
  asm volatile("s_waitcnt lgkmcnt(0)" ::: "memory");        \
  __builtin_amdgcn_s_barrier();                             \
  __builtin_amdgcn_sched_barrier(0);                        \
} while (0)

// ---------------------------------------------------------------------------
// Phase 1: out = x @ W_in + b_in + b_h (b_h folded). Grid 512 x 256 thr.
// MFMA 16x16x32 bf16. A[m][k]: m=lane&15, k=(lane>>4)*8+j; B same k, c=lane&15;
// D: c=lane&15, m=(lane>>4)*4+r.
// ---------------------------------------------------------------------------
__global__ __launch_bounds__(256, 1) void xproj_gemm(
    const float* __restrict__ x, const float* __restrict__ W_in,
    const float* __restrict__ b_in, const float* __restrict__ b_h,
    float* __restrict__ out) {
  const int tid  = threadIdx.x;
  const int lane = tid & 63;
  const int w    = tid >> 6;
  const int l15  = lane & 15;
  const int lg   = lane >> 4;
  const int koff = lg * 8;
  const int m0   = blockIdx.x * 128;

  short8 Bf[4][8];
#pragma unroll
  for (int n = 0; n < 4; ++n) {
    const int c = 64 * w + 16 * n + l15;
#pragma unroll
    for (int kk = 0; kk < 8; ++kk) {
      short8 bf;
#pragma unroll
      for (int j = 0; j < 8; ++j)
        bf[j] = (short)f2bf(W_in[(32 * kk + koff + j) * DH + c]);
      Bf[n][kk] = bf;
    }
  }
  float bin[4];
#pragma unroll
  for (int n = 0; n < 4; ++n) {
    const int c = 64 * w + 16 * n + l15;
    bin[n] = b_in[c] + b_h[c];
  }

  for (int slab = 0; slab < 8; ++slab) {
    const float* xr = x + (size_t)(m0 + slab * 16 + l15) * DH;
    short8 A[8];
#pragma unroll
    for (int kk = 0; kk < 8; ++kk) {
      f32x4 v0 = *(const f32x4*)(xr + 32 * kk + koff);
      f32x4 v1 = *(const f32x4*)(xr + 32 * kk + koff + 4);
      short8 a;
      a[0] = f2bf(v0[0]); a[1] = f2bf(v0[1]); a[2] = f2bf(v0[2]); a[3] = f2bf(v0[3]);
      a[4] = f2bf(v1[0]); a[5] = f2bf(v1[1]); a[6] = f2bf(v1[2]); a[7] = f2bf(v1[3]);
      A[kk] = a;
    }
    f32x4 acc[4];
#pragma unroll
    for (int n = 0; n < 4; ++n) acc[n] = (f32x4){0.f, 0.f, 0.f, 0.f};
#pragma unroll
    for (int kk = 0; kk < 8; ++kk)
#pragma unroll
      for (int n = 0; n < 4; ++n)
        acc[n] = __builtin_amdgcn_mfma_f32_16x16x32_bf16(A[kk], Bf[n][kk], acc[n], 0, 0, 0);
#pragma unroll
    for (int n = 0; n < 4; ++n) {
      const int c = 64 * w + 16 * n + l15;
#pragma unroll
      for (int r = 0; r < 4; ++r)
        out[(size_t)(m0 + slab * 16 + lg * 4 + r) * DH + c] = acc[n][r] + bin[n];
    }
  }
}

// ---------------------------------------------------------------------------
// Phase 2: serial scan, 16 BATCHES PACKED AS MFMA ROWS. Grid 2 x 512 thr.
// WG g owns batches 16g..16g+15; wave w owns cols [32w, 32w+32).
// Every MFMA row is a real batch -> the 128 MFMAs/step/CU (620 cyc of pipe,
// the fixed cost R1-R8 kept measuring) now serve 16 batches instead of 1.
// h_all: [16][256] bf16 in LDS, double-buffered, XOR-swizzled
//   byte(m,c) = m*512 + ((2c) ^ (m<<4))
// (unswizzled, the A-frag read lanes 0..15 stride 512B = 16-way bank
// conflict). x_proj: per-lane registers, 4-step lookahead, static-indexed
// via 4-step-unrolled loop. h stores: fire-and-forget global dwords.
// One barrier per step.
// ---------------------------------------------------------------------------
__global__ __launch_bounds__(512, 2) void rnn_scan(
    const float* __restrict__ h0, const float* __restrict__ W_h,
    float* __restrict__ out) {
  __shared__ __align__(16) unsigned short hb[2][16 * DH];

  const int tid  = threadIdx.x;
  const int lane = tid & 63;
  const int w    = tid >> 6;         // 0..7
  const int l15  = lane & 15;
  const int lg   = lane >> 4;        // 0..3
  const int g    = blockIdx.x;       // batch group

  // Global pointers: batch m = 4*lg + r, col base 32w + l15.
  float* sp0[4];
#pragma unroll
  for (int r = 0; r < 4; ++r) {
    const int m = 4 * lg + r;
    sp0[r] = out + (size_t)(16 * g + m) * T_LEN * DH + 32 * w + l15;
  }

  // Prologue xb prefetch for t = 0..3 (issued first, flies under W_h load).
  float xq[4][8];   // [slot][n*4+r]
#pragma unroll
  for (int s = 0; s < 4; ++s)
#pragma unroll
    for (int n = 0; n < 2; ++n)
#pragma unroll
      for (int r = 0; r < 4; ++r)
        xq[s][n * 4 + r] = sp0[r][(size_t)s * DH + 16 * n];

  // W_h bf16 fragments: wave w owns cols [32w, 32w+32) as 2 16-col tiles.
  const int koff = lg * 8;
  short8 Bf[2][8];
#pragma unroll
  for (int n = 0; n < 2; ++n) {
    const int c = 32 * w + 16 * n + l15;
#pragma unroll
    for (int kk = 0; kk < 8; ++kk) {
      short8 bf;
#pragma unroll
      for (int j = 0; j < 8; ++j)
        bf[j] = (short)f2bf(W_h[(32 * kk + koff + j) * DH + c]);
      Bf[n][kk] = bf;
    }
  }

  // t-invariant swizzled LDS byte offsets.
  int aoff[8];    // A-frag read: m = l15, c = 32kk + 8lg .. +8
#pragma unroll
  for (int kk = 0; kk < 8; ++kk)
    aoff[kk] = l15 * 512 + ((64 * kk + 16 * lg) ^ (l15 << 4));
  int woff[8];    // h write: m = 4lg+r, c = 32w + 16n + l15
#pragma unroll
  for (int n = 0; n < 2; ++n)
#pragma unroll
    for (int r = 0; r < 4; ++r) {
      const int m = 4 * lg + r;
      woff[n * 4 + r] = m * 512 + ((64 * w + 32 * n + 2 * l15) ^ (m << 4));
    }

  // Stage h0 (16 batches x 256) into hb[0], swizzled.
  {
    const int m  = tid >> 5;           // 0..15
    const int c0 = (tid & 31) * 8;     // 0..248
    const float* hp = h0 + (size_t)(16 * g + m) * DH + c0;
    short8 pk;
#pragma unroll
    for (int j = 0; j < 8; ++j) pk[j] = (short)f2bf(hp[j]);
    *(short8*)((char*)hb + m * 512 + ((2 * c0) ^ (m << 4))) = pk;
  }
  __syncthreads();

  float* sp = (float*)sp0[0];  // silence unused warn pattern (not used; kept simple)
  (void)sp;

  const float* lp[4];
#pragma unroll
  for (int r = 0; r < 4; ++r) lp[r] = sp0[r] + 4 * DH;

#define STEP(s, REFILL) do {                                                  \
    const int rb_ = (s) & 1, wb_ = ((s) + 1) & 1;                             \
    short8 A_[8];                                                             \
    _Pragma("unroll")                                                         \
    for (int kk = 0; kk < 8; ++kk)                                            \
      A_[kk] = *(const short8*)((const char*)hb + rb_ * 8192 + aoff[kk]);     \
    f32x4 ac_[2][2];                                                          \
    _Pragma("unroll")                                                         \
    for (int n = 0; n < 2; ++n) {                                             \
      ac_[n][0] = (f32x4){0.f, 0.f, 0.f, 0.f};                                \
      ac_[n][1] = (f32x4){0.f, 0.f, 0.f, 0.f};                                \
    }                                                                         \
    _Pragma("unroll")                                                         \
    for (int kk = 0; kk < 4; ++kk)                                            \
      _Pragma("unroll")                                                       \
      for (int n = 0; n < 2; ++n)                                             \
        ac_[n][0] = __builtin_amdgcn_mfma_f32_16x16x32_bf16(A_[kk], Bf[n][kk], ac_[n][0], 0, 0, 0); \
    _Pragma("unroll")                                                         \
    for (int kk = 4; kk < 8; ++kk)                                            \
      _Pragma("unroll")                                                       \
      for (int n = 0; n < 2; ++n)                                             \
        ac_[n][1] = __builtin_amdgcn_mfma_f32_16x16x32_bf16(A_[kk], Bf[n][kk], ac_[n][1], 0, 0, 0); \
    /* consume xb slot s */                                                   \
    f32x4 v_[2];                                                              \
    _Pragma("unroll")                                                         \
    for (int n = 0; n < 2; ++n)                                               \
      _Pragma("unroll")                                                       \
      for (int r = 0; r < 4; ++r)                                             \
        v_[n][r] = fmaxf(ac_[n][0][r] + ac_[n][1][r] + xq[s][n * 4 + r], 0.f);\
    /* refill slot s with t+4 */                                              \
    if (REFILL) {                                                             \
      _Pragma("unroll")                                                       \
      for (int n = 0; n < 2; ++n)                                             \
        _Pragma("unroll")                                                     \
        for (int r = 0; r < 4; ++r)                                           \
          xq[s][n * 4 + r] = lp[r][(size_t)(s) * DH + 16 * n];                \
    }                                                                         \
    /* write h (LDS, swizzled) + output (global, fire-and-forget) */          \
    _Pragma("unroll")                                                         \
    for (int n = 0; n < 2; ++n)                                               \
      _Pragma("unroll")                                                       \
      for (int r = 0; r < 4; ++r) {                                           \
        *(unsigned short*)((char*)hb + wb_ * 8192 + woff[n * 4 + r]) =        \
            f2bf(v_[n][r]);                                                   \
        sp0[r][(size_t)(s) * DH + 16 * n] = v_[n][r];                         \
      }                                                                       \
    STEP_BARRIER();                                                           \
  } while (0)

  for (int it = 0; it < T_LEN / 4; ++it) {
    const bool refill = (it + 1 < T_LEN / 4);
    STEP(0, refill);
    STEP(1, refill);
    STEP(2, refill);
    STEP(3, refill);
#pragma unroll
    for (int r = 0; r < 4; ++r) {
      sp0[r] += 4 * DH;
      lp[r]  += 4 * DH;
    }
  }
#undef STEP
}

extern "C" void kernel_launch(void* const* d_in, const int* in_sizes, int n_in,
                              void* d_out, int out_size, void* d_ws, size_t ws_size,
                              hipStream_t stream) {
  const float* x    = (const float*)d_in[0];
  const float* h0   = (const float*)d_in[1];
  const float* W_in = (const float*)d_in[2];
  const float* b_in = (const float*)d_in[3];
  const float* W_h  = (const float*)d_in[4];
  const float* b_h  = (const float*)d_in[5];
  float* out = (float*)d_out;

  hipLaunchKernelGGL(xproj_gemm, dim3(512), dim3(256), 0, stream, x, W_in, b_in, b_h, out);
  hipLaunchKernelGGL(rnn_scan, dim3(2), dim3(512), 0, stream, h0, W_h, out);
}

// Round 10
// 824.594 us; speedup vs baseline: 1.9884x; 1.9884x over previous
//
#include <hip/hip_runtime.h>

#define T_LEN 2048
#define DH 256
#define NCHUNK (T_LEN / 16)

typedef short short8 __attribute__((ext_vector_type(8)));
typedef float f32x4 __attribute__((ext_vector_type(4)));

__device__ __forceinline__ unsigned short f2bf(float f) {
  unsigned u = __builtin_bit_cast(unsigned, f);
  u += 0x7fffu + ((u >> 16) & 1u);   // round-to-nearest-even
  return (unsigned short)(u >> 16);
}

// Minimal step barrier: wait this wave's LDS ops (h writes), rendezvous,
// fence the scheduler. vmcnt deliberately NOT drained: xb refill loads and
// h stores stay in flight across steps (no cross-wave hazard through global).
#define STEP_BARRIER() do {                                 \
  asm volatile("s_waitcnt lgkmcnt(0)" ::: "memory");        \
  __builtin_amdgcn_s_barrier();                             \
  __builtin_amdgcn_sched_barrier(0);                        \
} while (0)

// ---------------------------------------------------------------------------
// Phase 1: out = x @ W_in + b_in + b_h (b_h folded). Grid 512 x 256 thr.
// MFMA 16x16x32 bf16. A[m][k]: m=lane&15, k=(lane>>4)*8+j; B same k, c=lane&15;
// D: c=lane&15, m=(lane>>4)*4+r.
// ---------------------------------------------------------------------------
__global__ __launch_bounds__(256, 1) void xproj_gemm(
    const float* __restrict__ x, const float* __restrict__ W_in,
    const float* __restrict__ b_in, const float* __restrict__ b_h,
    float* __restrict__ out) {
  const int tid  = threadIdx.x;
  const int lane = tid & 63;
  const int w    = tid >> 6;
  const int l15  = lane & 15;
  const int lg   = lane >> 4;
  const int koff = lg * 8;
  const int m0   = blockIdx.x * 128;

  short8 Bf[4][8];
#pragma unroll
  for (int n = 0; n < 4; ++n) {
    const int c = 64 * w + 16 * n + l15;
#pragma unroll
    for (int kk = 0; kk < 8; ++kk) {
      short8 bf;
#pragma unroll
      for (int j = 0; j < 8; ++j)
        bf[j] = (short)f2bf(W_in[(32 * kk + koff + j) * DH + c]);
      Bf[n][kk] = bf;
    }
  }
  float bin[4];
#pragma unroll
  for (int n = 0; n < 4; ++n) {
    const int c = 64 * w + 16 * n + l15;
    bin[n] = b_in[c] + b_h[c];
  }

  for (int slab = 0; slab < 8; ++slab) {
    const float* xr = x + (size_t)(m0 + slab * 16 + l15) * DH;
    short8 A[8];
#pragma unroll
    for (int kk = 0; kk < 8; ++kk) {
      f32x4 v0 = *(const f32x4*)(xr + 32 * kk + koff);
      f32x4 v1 = *(const f32x4*)(xr + 32 * kk + koff + 4);
      short8 a;
      a[0] = f2bf(v0[0]); a[1] = f2bf(v0[1]); a[2] = f2bf(v0[2]); a[3] = f2bf(v0[3]);
      a[4] = f2bf(v1[0]); a[5] = f2bf(v1[1]); a[6] = f2bf(v1[2]); a[7] = f2bf(v1[3]);
      A[kk] = a;
    }
    f32x4 acc[4];
#pragma unroll
    for (int n = 0; n < 4; ++n) acc[n] = (f32x4){0.f, 0.f, 0.f, 0.f};
#pragma unroll
    for (int kk = 0; kk < 8; ++kk)
#pragma unroll
      for (int n = 0; n < 4; ++n)
        acc[n] = __builtin_amdgcn_mfma_f32_16x16x32_bf16(A[kk], Bf[n][kk], acc[n], 0, 0, 0);
#pragma unroll
    for (int n = 0; n < 4; ++n) {
      const int c = 64 * w + 16 * n + l15;
#pragma unroll
      for (int r = 0; r < 4; ++r)
        out[(size_t)(m0 + slab * 16 + lg * 4 + r) * DH + c] = acc[n][r] + bin[n];
    }
  }
}

// ---------------------------------------------------------------------------
// Phase 2: serial scan. Grid 32 (one WG per batch) x 512 thr (8 waves).
// R8's minimal interval (LDS = 512B h double-buffer only, one barrier/step,
// xb in registers, fire-and-forget h stores) plus three overhead trims:
//   (1) s_setprio(1) around the MFMA block (2 waves/SIMD arbitration),
//   (2) chunk split into 4 sub-blocks with pointer bumps so every global
//       load/store offset fits the 13-bit signed immediate (no addr VALU),
//   (3) xq refill spread to 2 loads/step (was a 32-load burst at chunk end).
// ---------------------------------------------------------------------------
__global__ __launch_bounds__(512, 2) void rnn_scan(
    const float* __restrict__ h0, const float* __restrict__ W_h,
    float* __restrict__ out) {
  __shared__ __align__(16) unsigned short hb[2][DH];

  const int tid  = threadIdx.x;
  const int lane = tid & 63;
  const int w    = tid >> 6;         // 0..7
  const int l15  = lane & 15;
  const int lg   = lane >> 4;
  const int koff = lg * 8;
  const int b    = blockIdx.x;
  float* outb = out + (size_t)b * T_LEN * DH;
  float* obase = outb + 32 * w + l15;          // per-lane column base

  // xb chunk buffers (registers; indices static after full unroll).
  float xbA[32], xbB[32];

  // Prologue: fill a whole chunk's 32 xb values (lanes<16 only).
  auto ISSUE_XB = [&](int cc, float (&xb)[32]) {
    if (lane < 16) {
      const float* p = obase + (size_t)cc * 16 * DH;
#pragma unroll
      for (int s = 0; s < 16; ++s) {
        xb[2 * s]     = p[(size_t)s * DH];
        xb[2 * s + 1] = p[(size_t)s * DH + 16];
      }
    }
  };

  ISSUE_XB(0, xbA);   // fly under the W_h fragment load
  ISSUE_XB(1, xbB);

  // W_h bf16 fragments: wave w owns cols [32w, 32w+32) as 2 16-col tiles.
  short8 Bf[2][8];
#pragma unroll
  for (int n = 0; n < 2; ++n) {
    const int c = 32 * w + 16 * n + l15;
#pragma unroll
    for (int kk = 0; kk < 8; ++kk) {
      short8 bf;
#pragma unroll
      for (int j = 0; j < 8; ++j)
        bf[j] = (short)f2bf(W_h[(32 * kk + koff + j) * DH + c]);
      Bf[n][kk] = bf;
    }
  }

  if (tid < DH) hb[0][tid] = f2bf(h0[b * DH + tid]);
  __syncthreads();

  // A fragments: rows 1..15 zero, set ONCE; only l15==0 lanes overwrite.
  short8 A[8];
#pragma unroll
  for (int kk = 0; kk < 8; ++kk) A[kk] = (short8){0, 0, 0, 0, 0, 0, 0, 0};

  // One chunk = 16 steps as 4 sub-blocks of 4 (pointer bumps keep all global
  // offsets < 4 KiB). Per step: consume xq slot s, refill it from chunk cc+2
  // (clamped; tail refills are harmless dead loads).
  auto CHUNK = [&](int cc, float (&xq)[32]) {
    const int ccl = (cc + 2 < NCHUNK) ? cc + 2 : NCHUNK - 1;
    float* orow = obase + (size_t)cc * 16 * DH;
    const float* rrow = obase + (size_t)ccl * 16 * DH;
#pragma unroll
    for (int sb = 0; sb < 4; ++sb) {
#pragma unroll
      for (int sp = 0; sp < 4; ++sp) {
        const int s = 4 * sb + sp;
        const unsigned short* hbR = hb[s & 1];
        unsigned short* hbW = hb[(s + 1) & 1];
        if (l15 == 0) {
#pragma unroll
          for (int kk = 0; kk < 8; ++kk)
            A[kk] = *(const short8*)(hbR + 32 * kk + koff);
        }

        // 16 MFMAs: 2 col-tiles x 2 sub-accumulators of depth 4.
        f32x4 ac[2][2];
#pragma unroll
        for (int n = 0; n < 2; ++n) {
          ac[n][0] = (f32x4){0.f, 0.f, 0.f, 0.f};
          ac[n][1] = (f32x4){0.f, 0.f, 0.f, 0.f};
        }
        __builtin_amdgcn_s_setprio(1);
#pragma unroll
        for (int kk = 0; kk < 4; ++kk)
#pragma unroll
          for (int n = 0; n < 2; ++n)
            ac[n][0] = __builtin_amdgcn_mfma_f32_16x16x32_bf16(A[kk], Bf[n][kk], ac[n][0], 0, 0, 0);
#pragma unroll
        for (int kk = 4; kk < 8; ++kk)
#pragma unroll
          for (int n = 0; n < 2; ++n)
            ac[n][1] = __builtin_amdgcn_mfma_f32_16x16x32_bf16(A[kk], Bf[n][kk], ac[n][1], 0, 0, 0);
        __builtin_amdgcn_s_setprio(0);

        // Valid output row m=0 -> lanes 0..15, element 0.
        if (lane < 16) {
          float v0 = (ac[0][0][0] + ac[0][1][0]) + xq[2 * s];
          float v1 = (ac[1][0][0] + ac[1][1][0]) + xq[2 * s + 1];
          v0 = fmaxf(v0, 0.0f);
          v1 = fmaxf(v1, 0.0f);
          hbW[32 * w + lane]      = f2bf(v0);   // next step's critical dep
          hbW[32 * w + 16 + lane] = f2bf(v1);
          orow[(size_t)sp * DH]      = v0;      // fire-and-forget
          orow[(size_t)sp * DH + 16] = v1;
          xq[2 * s]     = rrow[(size_t)sp * DH];        // refill (2 loads)
          xq[2 * s + 1] = rrow[(size_t)sp * DH + 16];
        }
        STEP_BARRIER();
      }
      orow += 4 * DH;
      rrow += 4 * DH;
    }
  };

  for (int c2 = 0; c2 < NCHUNK; c2 += 2) {
    CHUNK(c2, xbA);
    CHUNK(c2 + 1, xbB);
  }
}

extern "C" void kernel_launch(void* const* d_in, const int* in_sizes, int n_in,
                              void* d_out, int out_size, void* d_ws, size_t ws_size,
                              hipStream_t stream) {
  const float* x    = (const float*)d_in[0];
  const float* h0   = (const float*)d_in[1];
  const float* W_in = (const float*)d_in[2];
  const float* b_in = (const float*)d_in[3];
  const float* W_h  = (const float*)d_in[4];
  const float* b_h  = (const float*)d_in[5];
  float* out = (float*)d_out;

  hipLaunchKernelGGL(xproj_gemm, dim3(512), dim3(256), 0, stream, x, W_in, b_in, b_h, out);
  hipLaunchKernelGGL(rnn_scan, dim3(32), dim3(512), 0, stream, h0, W_h, out);
}